// Round 18
// baseline (168.750 us; speedup 1.0000x reference)
//
#include <hip/hip_runtime.h>

typedef unsigned short ushortT;
typedef __attribute__((ext_vector_type(8))) short short8;
typedef __attribute__((ext_vector_type(4))) short short4v;
typedef __attribute__((ext_vector_type(8))) __bf16 bf16x8;
typedef __attribute__((ext_vector_type(4))) float f32x4;

__device__ __forceinline__ float bf2f(ushortT u) {
    unsigned int x = ((unsigned int)u) << 16;
    return __builtin_bit_cast(float, x);
}
__device__ __forceinline__ ushortT f2bf(float f) {
    unsigned int x = __builtin_bit_cast(unsigned int, f);
    unsigned int r = (x + 0x7FFFu + ((x >> 16) & 1u)) >> 16;
    return (ushortT)r;
}

__device__ __forceinline__ void gload_lds16(const void* g, void* l) {
    __builtin_amdgcn_global_load_lds(
        (const __attribute__((address_space(1))) void*)g,
        (__attribute__((address_space(3))) void*)l, 16, 0, 0);
}

// ---------------------------------------------------------------------------
// 1) prep_fused: [0,512) wct_part split-K x8; [512,1088) permute_fc1.
// ---------------------------------------------------------------------------
__global__ __launch_bounds__(256)
void prep_fused(const float* __restrict__ w_c1, const float* __restrict__ w_c2,
                const float* __restrict__ w_fc1,
                float* __restrict__ wpart, ushortT* __restrict__ wpt)
{
    __shared__ __align__(16) char smem[33280];
    const int blk = blockIdx.x;
    const int tid = threadIdx.x;

    if (blk < 512) {
        auto w2s = reinterpret_cast<float(*)[65]>(smem);           // [64][65]
        auto w1s = reinterpret_cast<float(*)[65]>(smem + 16640);   // [64][65]
        const int idx = blk;
        const int o0 = (idx & 3) * 64;
        const int c0 = ((idx >> 2) & 15) * 64;
        const int z  = idx >> 6;             // 0..7
        const int m0 = z * 64;
        const int ty = tid >> 4, tx = tid & 15;
        float acc[4][4] = {};
        #pragma unroll
        for (int c4 = 0; c4 < 4; ++c4) {
            int id2 = c4 * 256 + tid;
            int row = id2 >> 4, f4 = id2 & 15;
            float4 v = *reinterpret_cast<const float4*>(
                w_c2 + (size_t)(o0 + row) * 512 + m0 + f4 * 4);
            w2s[row][f4*4+0] = v.x; w2s[row][f4*4+1] = v.y;
            w2s[row][f4*4+2] = v.z; w2s[row][f4*4+3] = v.w;
            float4 u = *reinterpret_cast<const float4*>(
                w_c1 + (size_t)(m0 + row) * 1024 + c0 + f4 * 4);
            w1s[row][f4*4+0] = u.x; w1s[row][f4*4+1] = u.y;
            w1s[row][f4*4+2] = u.z; w1s[row][f4*4+3] = u.w;
        }
        __syncthreads();
        for (int m = 0; m < 64; ++m) {
            float a[4], b[4];
            #pragma unroll
            for (int i = 0; i < 4; ++i) a[i] = w2s[ty*4+i][m];
            #pragma unroll
            for (int j = 0; j < 4; ++j) b[j] = w1s[m][tx*4+j];
            #pragma unroll
            for (int i = 0; i < 4; ++i)
                #pragma unroll
                for (int j = 0; j < 4; ++j) acc[i][j] = fmaf(a[i], b[j], acc[i][j]);
        }
        float* dst = wpart + (size_t)z * 262144;
        #pragma unroll
        for (int i = 0; i < 4; ++i) {
            float4 ov = { acc[i][0], acc[i][1], acc[i][2], acc[i][3] };
            *reinterpret_cast<float4*>(dst + (size_t)(o0 + ty*4 + i) * 1024 + c0 + tx*4) = ov;
        }
    } else {
        auto tile = reinterpret_cast<float(*)[65]>(smem);          // [64][65]
        const int idx = blk - 512;                                  // 0..575
        const int cib = idx % 36;
        const int ci0 = cib * 64;
        const int j0  = (idx / 36) * 64;
        const int hw  = ci0 >> 8;
        const int o0  = ci0 & 255;
        #pragma unroll
        for (int c4 = 0; c4 < 4; ++c4) {
            int id2 = c4 * 256 + tid;
            int row = id2 >> 4;
            int f4  = id2 & 15;
            float4 v = *reinterpret_cast<const float4*>(
                w_fc1 + (size_t)((o0 + row) * 9 + hw) * 1024 + j0 + f4 * 4);
            tile[row][f4*4+0] = v.x; tile[row][f4*4+1] = v.y;
            tile[row][f4*4+2] = v.z; tile[row][f4*4+3] = v.w;
        }
        __syncthreads();
        #pragma unroll
        for (int c4 = 0; c4 < 4; ++c4) {
            int id2 = c4 * 256 + tid;
            int j   = id2 >> 4;
            int og  = id2 & 15;
            short4v ov;
            #pragma unroll
            for (int i = 0; i < 4; ++i) ov[i] = (short)f2bf(tile[og*4+i][j]);
            *reinterpret_cast<short4v*>(wpt + (size_t)(j0 + j) * 2304 + ci0 + og*4) = ov;
        }
    }
}

// ---------------------------------------------------------------------------
// 2) wct_reduce8: Wct_t[i] = bf16(sum_{z<8} part[z][i]), float4-vectorized.
// ---------------------------------------------------------------------------
__global__ __launch_bounds__(256)
void wct_reduce8(const float* __restrict__ part, ushortT* __restrict__ Wct_t)
{
    const int i = blockIdx.x * 256 + threadIdx.x;       // 65536 float4-groups
    float4 s = *reinterpret_cast<const float4*>(part + (size_t)i * 4);
    #pragma unroll
    for (int z = 1; z < 8; ++z) {
        float4 v = *reinterpret_cast<const float4*>(part + (size_t)z * 262144 + (size_t)i * 4);
        s.x += v.x; s.y += v.y; s.z += v.z; s.w += v.w;
    }
    short4v ov = { (short)f2bf(s.x), (short)f2bf(s.y),
                   (short)f2bf(s.z), (short)f2bf(s.w) };
    *reinterpret_cast<short4v*>(Wct_t + (size_t)i * 4) = ov;
}

// ---------------------------------------------------------------------------
// 3) conv_direct v2: fmap2[gp][o] = sum_c fmap[b(gp)][c][p(gp)] * Wct_t[o][c]
//    P staged f32 via DMA + XOR slot swizzle (proven conflict-free, R17);
//    W fragments DIRECT FROM GLOBAL (L2-hot, gemm-v4-proven prefetch) -> LDS
//    halves to 32KB -> 3 blocks/CU (the R17 limiter was occupancy=16%).
// ---------------------------------------------------------------------------
__global__ __launch_bounds__(256, 3)
void conv_direct(const float* __restrict__ fmap, const ushortT* __restrict__ Wct_t,
                 ushortT* __restrict__ fmap2)
{
    __shared__ float Pf[2][64 * 64];        // 16KB x2: [c][16 slots x 4 f32]
    const int tid  = threadIdx.x;
    const int wid  = tid >> 6;
    const int lane = tid & 63;
    const int fr   = lane & 15;
    const int kq   = lane >> 4;

    // 784 blocks = 392 gp-tiles x 2 o-halves; pairs adjacent on one XCD.
    const int i   = blockIdx.x;
    const int w   = (i & 7) * 98 + (i >> 3);
    const int gp0 = (w >> 1) * 64;
    const int o0  = (w & 1) * 128;

    // hoisted k0-invariant P staging sources (XOR slot swizzle on source)
    const float* psrc[4];
    #pragma unroll
    for (int q = 0; q < 4; ++q) {
        int id = q * 256 + tid;
        int c  = id >> 4;                       // 0..63
        int js = id & 15;                       // slot
        int x  = (c + 4 * (c >> 3)) & 15;
        int j  = js ^ x;                        // granule within tile
        int gg = (gp0 >> 2) + j;                // global granule
        int bb = gg / 49;
        int p4g = gg - bb * 49;
        psrc[q] = fmap + ((size_t)bb * 1024 + c) * 196 + p4g * 4;
    }

    auto stage = [&](int k0, int buf) {
        #pragma unroll
        for (int q = 0; q < 4; ++q) {
            int id = q * 256 + tid;
            gload_lds16(psrc[q] + (size_t)k0 * 196, (char*)&Pf[buf][0] + id * 16);
        }
    };

    // W direct from global: rows o0+wid*32+{0,16}+fr, 16B chunks at kq*8.
    const ushortT* wbase = Wct_t + (size_t)(o0 + wid * 32 + fr) * 1024 + kq * 8;
    auto loadW = [&](int k0, bf16x8& w00, bf16x8& w01, bf16x8& w10, bf16x8& w11) {
        w00 = *reinterpret_cast<const bf16x8*>(wbase + k0);
        w01 = *reinterpret_cast<const bf16x8*>(wbase + k0 + 32);
        w10 = *reinterpret_cast<const bf16x8*>(wbase + (size_t)16 * 1024 + k0);
        w11 = *reinterpret_cast<const bf16x8*>(wbase + (size_t)16 * 1024 + k0 + 32);
    };

    const int p4b = fr >> 2, pr = fr & 3;
    auto aread = [&](const float* PB, int m, int ks) -> bf16x8 {
        const int p4 = m * 4 + p4b;
        bf16x8 a;
        #pragma unroll
        for (int i2 = 0; i2 < 8; ++i2) {
            int x = (i2 + 12 * kq) & 15;        // == (c+4*(c>>3))&15 for this c
            int c = ks * 32 + kq * 8 + i2;
            a[i2] = (__bf16)PB[(c << 6) + ((p4 ^ x) << 2) + pr];
        }
        return a;
    };

    f32x4 acc[4][2];
    #pragma unroll
    for (int m = 0; m < 4; ++m) { acc[m][0] = (f32x4){0,0,0,0}; acc[m][1] = (f32x4){0,0,0,0}; }

    auto domfma = [&](const float* PB, bf16x8 w00, bf16x8 w01, bf16x8 w10, bf16x8 w11) {
        #pragma unroll
        for (int m = 0; m < 4; ++m) {
            bf16x8 a0 = aread(PB, m, 0);
            acc[m][0] = __builtin_amdgcn_mfma_f32_16x16x32_bf16(a0, w00, acc[m][0], 0, 0, 0);
            acc[m][1] = __builtin_amdgcn_mfma_f32_16x16x32_bf16(a0, w10, acc[m][1], 0, 0, 0);
            bf16x8 a1 = aread(PB, m, 1);
            acc[m][0] = __builtin_amdgcn_mfma_f32_16x16x32_bf16(a1, w01, acc[m][0], 0, 0, 0);
            acc[m][1] = __builtin_amdgcn_mfma_f32_16x16x32_bf16(a1, w11, acc[m][1], 0, 0, 0);
        }
    };

    bf16x8 wA00, wA01, wA10, wA11, wB00, wB01, wB10, wB11;
    stage(0, 0);
    loadW(0, wA00, wA01, wA10, wA11);
    __syncthreads();

    #pragma unroll 1
    for (int s = 0; s < 8; ++s) {
        const int t = 2 * s;
        if (t + 1 < 16) { stage((t + 1) * 64, 1); loadW((t + 1) * 64, wB00, wB01, wB10, wB11); }
        domfma(Pf[0], wA00, wA01, wA10, wA11);
        __syncthreads();
        if (t + 2 < 16) { stage((t + 2) * 64, 0); loadW((t + 2) * 64, wA00, wA01, wA10, wA11); }
        domfma(Pf[1], wB00, wB01, wB10, wB11);
        __syncthreads();
    }

    // D: col=fr (o), row=kq*4+jj (gp within m-block)  [m89/m91]
    #pragma unroll
    for (int m = 0; m < 4; ++m) {
        const int gp = gp0 + m * 16 + kq * 4;
        #pragma unroll
        for (int n = 0; n < 2; ++n) {
            const int o = o0 + wid * 32 + n * 16 + fr;
            #pragma unroll
            for (int jj = 0; jj < 4; ++jj)
                fmap2[(size_t)(gp + jj) * 256 + o] = f2bf(acc[m][n][jj]);
        }
    }
}

// ---------------------------------------------------------------------------
// 4) roi_lite: fmap2 bf16 [25088][256] -> pooled [4096][9*256] bf16
// ---------------------------------------------------------------------------
__global__ __launch_bounds__(256)
void roi_lite(const ushortT* __restrict__ fmap2, const float* __restrict__ boxes,
              ushortT* __restrict__ pooled)
{
    __shared__ ushortT tile[196][72];
    const int b   = blockIdx.x >> 2;
    const int o0  = (blockIdx.x & 3) << 6;
    const int tid = threadIdx.x;

    const ushortT* src = fmap2 + (size_t)b * 196 * 256 + o0;
    #pragma unroll
    for (int i = 0; i < 7; ++i) {
        int chunk = tid + (i << 8);
        if (chunk < 1568) {
            int p  = chunk >> 3;
            int c8 = (chunk & 7) << 3;
            short8 v = *reinterpret_cast<const short8*>(src + (size_t)p * 256 + c8);
            *reinterpret_cast<short8*>(&tile[p][c8]) = v;
        }
    }
    __syncthreads();

    const int box = tid >> 3;
    const int ch8 = (tid & 7) << 3;
    const int k   = (b << 5) + box;
    const float* bx = boxes + (size_t)k * 4;
    float x1 = fminf(fmaxf(bx[0], 0.f), 14.f);
    float y1 = fminf(fmaxf(bx[1], 0.f), 14.f);
    float x2 = fminf(fmaxf(bx[2], 0.f), 14.f);
    float y2 = fminf(fmaxf(bx[3], 0.f), 14.f);
    float bw = fmaxf(x2 - x1, 1.f) * (1.0f / 3.0f);
    float bh = fmaxf(y2 - y1, 1.f) * (1.0f / 3.0f);

    int   ylo[6], xlo[6];
    float wylo[6], wyhi[6], wxlo[6], wxhi[6];
    #pragma unroll
    for (int i = 0; i < 6; ++i) {
        float off = (i & 1) ? 0.75f : 0.25f;
        float pf  = (float)(i >> 1);
        float yc = y1 + (pf + off) * bh;
        bool  vy = (yc > -1.0f) && (yc < 14.f);
        float cy = fminf(fmaxf(yc, 0.f), 13.f);
        int   lo = (int)floorf(cy); if (lo > 12) lo = 12;
        float fy = cy - (float)lo;
        ylo[i]  = lo;
        wylo[i] = vy ? 1.f - fy : 0.f;
        wyhi[i] = vy ? fy       : 0.f;
        float xc = x1 + (pf + off) * bw;
        bool  vx = (xc > -1.0f) && (xc < 14.f);
        float cx = fminf(fmaxf(xc, 0.f), 13.f);
        int   lx = (int)floorf(cx); if (lx > 12) lx = 12;
        float fx = cx - (float)lx;
        xlo[i]  = lx;
        wxlo[i] = vx ? 1.f - fx : 0.f;
        wxhi[i] = vx ? fx       : 0.f;
    }

    float acc[3][3][8] = {};
    #pragma unroll
    for (int i = 0; i < 6; ++i) {
        #pragma unroll
        for (int j = 0; j < 6; ++j) {
            const int plo = ylo[i] * 14 + xlo[j];
            const float w00 = wylo[i] * wxlo[j];
            const float w01 = wylo[i] * wxhi[j];
            const float w10 = wyhi[i] * wxlo[j];
            const float w11 = wyhi[i] * wxhi[j];
            short8 v00 = *reinterpret_cast<const short8*>(&tile[plo][ch8]);
            short8 v01 = *reinterpret_cast<const short8*>(&tile[plo + 1][ch8]);
            short8 v10 = *reinterpret_cast<const short8*>(&tile[plo + 14][ch8]);
            short8 v11 = *reinterpret_cast<const short8*>(&tile[plo + 15][ch8]);
            #pragma unroll
            for (int c = 0; c < 8; ++c) {
                float a = acc[i >> 1][j >> 1][c];
                a = fmaf(bf2f((ushortT)v00[c]), w00, a);
                a = fmaf(bf2f((ushortT)v01[c]), w01, a);
                a = fmaf(bf2f((ushortT)v10[c]), w10, a);
                a = fmaf(bf2f((ushortT)v11[c]), w11, a);
                acc[i >> 1][j >> 1][c] = a;
            }
        }
    }

    ushortT* outp = pooled + (size_t)k * 2304 + o0 + ch8;
    #pragma unroll
    for (int p = 0; p < 3; ++p) {
        #pragma unroll
        for (int q = 0; q < 3; ++q) {
            short8 ov;
            #pragma unroll
            for (int c = 0; c < 8; ++c) ov[c] = (short)f2bf(acc[p][q][c] * 0.25f);
            *reinterpret_cast<short8*>(outp + (size_t)(p * 3 + q) * 256) = ov;
        }
    }
}

// ---------------------------------------------------------------------------
// 5) gemm_mfma v4 (fc1): C[M][N] = A[M][K]*Bt[N][K]^T, tile 128x64, swizzled.
// ---------------------------------------------------------------------------
template<int RELU, int BIAS>
__global__ __launch_bounds__(256, 2)
void gemm_mfma(const ushortT* __restrict__ A, const ushortT* __restrict__ Bt,
               ushortT* __restrict__ C, const float* __restrict__ bias,
               int M, int N, int K)
{
    __shared__ ushortT As[2][128 * 64];    // 16KB x2
    const int tid  = threadIdx.x;
    const int wid  = tid >> 6;
    const int lane = tid & 63;
    const int ncolb = N >> 6;
    const int nblk  = (M >> 7) * ncolb;
    const int cpx   = nblk >> 3;
    const int i     = blockIdx.x;
    const int w     = (i & 7) * cpx + (i >> 3);
    const size_t row0 = (size_t)(w / ncolb) * 128;
    const size_t col0 = (size_t)(w % ncolb) * 64;

    const ushortT* agbase = A + row0 * K;
    auto stage = [&](int k0, int buf) {
        #pragma unroll
        for (int q = 0; q < 4; ++q) {
            int id  = q * 256 + tid;
            int row = id >> 3;
            int kcs = (id & 7) ^ (row & 7);
            gload_lds16(agbase + (size_t)row * K + k0 + kcs * 8,
                        As[buf] + id * 8);
        }
    };

    const int fr = lane & 15;
    const int kq = lane >> 4;
    const int rx = fr & 7;
    auto lda = [&](const ushortT* Ab, int m, int s) -> bf16x8 {
        const int r = m * 16 + fr;
        const int c = (s << 2) + kq;
        return *reinterpret_cast<const bf16x8*>(&Ab[(r << 6) + ((c ^ rx) << 3)]);
    };

    const ushortT* bbase = Bt + (col0 + wid * 16 + fr) * (size_t)K + kq * 8;
    auto loadB2 = [&](int k0, bf16x8& r0, bf16x8& r1) {
        r0 = *reinterpret_cast<const bf16x8*>(bbase + k0);
        r1 = *reinterpret_cast<const bf16x8*>(bbase + k0 + 32);
    };

    f32x4 acc[8];
    #pragma unroll
    for (int m = 0; m < 8; ++m) acc[m] = (f32x4){0,0,0,0};

    auto domfma = [&](const ushortT* Ab, bf16x8 b0, bf16x8 b1) {
        #pragma unroll
        for (int m = 0; m < 8; ++m) {
            acc[m] = __builtin_amdgcn_mfma_f32_16x16x32_bf16(lda(Ab, m, 0), b0, acc[m], 0, 0, 0);
            acc[m] = __builtin_amdgcn_mfma_f32_16x16x32_bf16(lda(Ab, m, 1), b1, acc[m], 0, 0, 0);
        }
    };

    const int nsteps = K >> 6;
    bf16x8 bA0, bA1, bB0, bB1;
    stage(0, 0);
    loadB2(0, bA0, bA1);
    __syncthreads();

    #pragma unroll 1
    for (int s = 0; s < (nsteps >> 1); ++s) {
        const int t = 2 * s;
        if (t + 1 < nsteps) { stage((t + 1) * 64, 1); loadB2((t + 1) * 64, bB0, bB1); }
        domfma(As[0], bA0, bA1);
        __syncthreads();
        if (t + 2 < nsteps) { stage((t + 2) * 64, 0); loadB2((t + 2) * 64, bA0, bA1); }
        domfma(As[1], bB0, bB1);
        __syncthreads();
    }

    const int orow = kq * 4;
    const size_t col = col0 + wid * 16 + fr;
    float bv = 0.f;
    if (BIAS) bv = bias[col];
    #pragma unroll
    for (int m = 0; m < 8; ++m) {
        const size_t rbase = row0 + m * 16 + orow;
        #pragma unroll
        for (int j = 0; j < 4; ++j) {
            float v = acc[m][j] + bv;
            if (RELU) v = fmaxf(v, 0.f);
            C[(rbase + j) * N + col] = f2bf(v);
        }
    }
}

// ---------------------------------------------------------------------------
// 6) fc2: out[4096][27] f32 = h[4096][1024] @ w[1024][27] + b
// ---------------------------------------------------------------------------
__global__ __launch_bounds__(256)
void fc2_kernel(const ushortT* __restrict__ h, const float* __restrict__ w,
                const float* __restrict__ bias, float* __restrict__ out)
{
    __shared__ float   Wsm[128][32];
    __shared__ ushortT Hs[16][136];
    const int tid  = threadIdx.x;
    const int row0 = blockIdx.x * 16;
    const int r    = tid >> 4;
    const int jg   = tid & 15;
    float accx = 0.f, accy = 0.f;

    const int kk2  = tid >> 1;
    const int half = tid & 1;

    for (int k0 = 0; k0 < 1024; k0 += 128) {
        if (half == 0) {
            #pragma unroll
            for (int j = 0; j < 14; ++j)
                Wsm[kk2][j] = w[(size_t)(k0 + kk2) * 27 + j];
        } else {
            #pragma unroll
            for (int j = 14; j < 27; ++j)
                Wsm[kk2][j] = w[(size_t)(k0 + kk2) * 27 + j];
            #pragma unroll
            for (int j = 27; j < 32; ++j) Wsm[kk2][j] = 0.f;
        }
        {
            int hr = tid >> 4, hc = tid & 15;
            short8 v = *reinterpret_cast<const short8*>(
                h + (size_t)(row0 + hr) * 1024 + k0 + hc * 8);
            *reinterpret_cast<short8*>(&Hs[hr][hc * 8]) = v;
        }
        __syncthreads();
        #pragma unroll 8
        for (int kk = 0; kk < 128; ++kk) {
            float  hv = bf2f(Hs[r][kk]);
            float2 wv = *reinterpret_cast<const float2*>(&Wsm[kk][jg * 2]);
            accx = fmaf(hv, wv.x, accx);
            accy = fmaf(hv, wv.y, accy);
        }
        __syncthreads();
    }
    const int j0 = jg * 2;
    float* op = out + (size_t)(row0 + r) * 27;
    if (j0 < 27)     op[j0]     = accx + bias[j0];
    if (j0 + 1 < 27) op[j0 + 1] = accy + bias[j0 + 1];
}

// ---------------------------------------------------------------------------
extern "C" void kernel_launch(void* const* d_in, const int* in_sizes, int n_in,
                              void* d_out, int out_size, void* d_ws, size_t ws_size,
                              hipStream_t stream)
{
    (void)in_sizes; (void)n_in; (void)out_size; (void)ws_size;
    const float* fmap  = (const float*)d_in[0];
    const float* boxes = (const float*)d_in[1];
    const float* w_c1  = (const float*)d_in[2];
    const float* w_c2  = (const float*)d_in[3];
    const float* w_fc1 = (const float*)d_in[4];
    const float* b_fc1 = (const float*)d_in[5];
    const float* w_fc2 = (const float*)d_in[6];
    const float* b_fc2 = (const float*)d_in[7];
    float* out = (float*)d_out;

    char* ws = (char*)d_ws;
    size_t off = 0;
    ushortT* fmap2  = (ushortT*)(ws + off); off += (size_t)25088 * 256 * 2;   // 12,845,056
    ushortT* pooled = (ushortT*)(ws + off); off += (size_t)4096 * 2304 * 2;   // 18,874,368
    ushortT* hbuf   = (ushortT*)(ws + off); off += (size_t)4096 * 1024 * 2;   //  8,388,608
    ushortT* Wct_t  = (ushortT*)(ws + off); off += (size_t)256 * 1024 * 2;    //    524,288
    ushortT* wp_t   = (ushortT*)(ws + off); off += (size_t)1024 * 2304 * 2;   //  4,718,592
    float*   wpart  = (float*)(ws + off);   off += (size_t)8 * 262144 * 4;    //  8,388,608

    hipLaunchKernelGGL(prep_fused,  dim3(1088), dim3(256), 0, stream,
                       w_c1, w_c2, w_fc1, wpart, wp_t);
    hipLaunchKernelGGL(wct_reduce8, dim3(256),  dim3(256), 0, stream, wpart, Wct_t);

    // conv (transpose fused): fmap2[25088 x 256] from fmap f32 directly
    hipLaunchKernelGGL(conv_direct, dim3(784),  dim3(256), 0, stream,
                       fmap, Wct_t, fmap2);
    hipLaunchKernelGGL(roi_lite,    dim3(512),  dim3(256), 0, stream, fmap2, boxes, pooled);
    // fc1: hbuf[4096 x 1024] = pooled[4096 x 2304] * wp_t[1024 x 2304]^T (+bias, relu)
    hipLaunchKernelGGL((gemm_mfma<1,1>), dim3(512), dim3(256), 0, stream,
                       pooled, wp_t, hbuf, b_fc1, 4096, 1024, 2304);
    hipLaunchKernelGGL(fc2_kernel,  dim3(256),  dim3(256), 0, stream,
                       hbuf, w_fc2, b_fc2, out);
}

// Round 19
// 132.701 us; speedup vs baseline: 1.2717x; 1.2717x over previous
//
#include <hip/hip_runtime.h>

typedef unsigned short ushortT;
typedef __attribute__((ext_vector_type(8))) short short8;
typedef __attribute__((ext_vector_type(4))) short short4v;
typedef __attribute__((ext_vector_type(8))) __bf16 bf16x8;
typedef __attribute__((ext_vector_type(4))) float f32x4;

__device__ __forceinline__ float bf2f(ushortT u) {
    unsigned int x = ((unsigned int)u) << 16;
    return __builtin_bit_cast(float, x);
}
__device__ __forceinline__ ushortT f2bf(float f) {
    unsigned int x = __builtin_bit_cast(unsigned int, f);
    unsigned int r = (x + 0x7FFFu + ((x >> 16) & 1u)) >> 16;
    return (ushortT)r;
}

__device__ __forceinline__ void gload_lds16(const void* g, void* l) {
    __builtin_amdgcn_global_load_lds(
        (const __attribute__((address_space(1))) void*)g,
        (__attribute__((address_space(3))) void*)l, 16, 0, 0);
}

// ---------------------------------------------------------------------------
// 1) prep_fused: [0,512) wct_part split-K x8; [512,1088) permute_fc1.
// ---------------------------------------------------------------------------
__global__ __launch_bounds__(256)
void prep_fused(const float* __restrict__ w_c1, const float* __restrict__ w_c2,
                const float* __restrict__ w_fc1,
                float* __restrict__ wpart, ushortT* __restrict__ wpt)
{
    __shared__ __align__(16) char smem[33280];
    const int blk = blockIdx.x;
    const int tid = threadIdx.x;

    if (blk < 512) {
        auto w2s = reinterpret_cast<float(*)[65]>(smem);           // [64][65]
        auto w1s = reinterpret_cast<float(*)[65]>(smem + 16640);   // [64][65]
        const int idx = blk;
        const int o0 = (idx & 3) * 64;
        const int c0 = ((idx >> 2) & 15) * 64;
        const int z  = idx >> 6;             // 0..7
        const int m0 = z * 64;
        const int ty = tid >> 4, tx = tid & 15;
        float acc[4][4] = {};
        #pragma unroll
        for (int c4 = 0; c4 < 4; ++c4) {
            int id2 = c4 * 256 + tid;
            int row = id2 >> 4, f4 = id2 & 15;
            float4 v = *reinterpret_cast<const float4*>(
                w_c2 + (size_t)(o0 + row) * 512 + m0 + f4 * 4);
            w2s[row][f4*4+0] = v.x; w2s[row][f4*4+1] = v.y;
            w2s[row][f4*4+2] = v.z; w2s[row][f4*4+3] = v.w;
            float4 u = *reinterpret_cast<const float4*>(
                w_c1 + (size_t)(m0 + row) * 1024 + c0 + f4 * 4);
            w1s[row][f4*4+0] = u.x; w1s[row][f4*4+1] = u.y;
            w1s[row][f4*4+2] = u.z; w1s[row][f4*4+3] = u.w;
        }
        __syncthreads();
        for (int m = 0; m < 64; ++m) {
            float a[4], b[4];
            #pragma unroll
            for (int i = 0; i < 4; ++i) a[i] = w2s[ty*4+i][m];
            #pragma unroll
            for (int j = 0; j < 4; ++j) b[j] = w1s[m][tx*4+j];
            #pragma unroll
            for (int i = 0; i < 4; ++i)
                #pragma unroll
                for (int j = 0; j < 4; ++j) acc[i][j] = fmaf(a[i], b[j], acc[i][j]);
        }
        float* dst = wpart + (size_t)z * 262144;
        #pragma unroll
        for (int i = 0; i < 4; ++i) {
            float4 ov = { acc[i][0], acc[i][1], acc[i][2], acc[i][3] };
            *reinterpret_cast<float4*>(dst + (size_t)(o0 + ty*4 + i) * 1024 + c0 + tx*4) = ov;
        }
    } else {
        auto tile = reinterpret_cast<float(*)[65]>(smem);          // [64][65]
        const int idx = blk - 512;                                  // 0..575
        const int cib = idx % 36;
        const int ci0 = cib * 64;
        const int j0  = (idx / 36) * 64;
        const int hw  = ci0 >> 8;
        const int o0  = ci0 & 255;
        #pragma unroll
        for (int c4 = 0; c4 < 4; ++c4) {
            int id2 = c4 * 256 + tid;
            int row = id2 >> 4;
            int f4  = id2 & 15;
            float4 v = *reinterpret_cast<const float4*>(
                w_fc1 + (size_t)((o0 + row) * 9 + hw) * 1024 + j0 + f4 * 4);
            tile[row][f4*4+0] = v.x; tile[row][f4*4+1] = v.y;
            tile[row][f4*4+2] = v.z; tile[row][f4*4+3] = v.w;
        }
        __syncthreads();
        #pragma unroll
        for (int c4 = 0; c4 < 4; ++c4) {
            int id2 = c4 * 256 + tid;
            int j   = id2 >> 4;
            int og  = id2 & 15;
            short4v ov;
            #pragma unroll
            for (int i = 0; i < 4; ++i) ov[i] = (short)f2bf(tile[og*4+i][j]);
            *reinterpret_cast<short4v*>(wpt + (size_t)(j0 + j) * 2304 + ci0 + og*4) = ov;
        }
    }
}

// ---------------------------------------------------------------------------
// 2) wct_reduce8: Wct_t[i] = bf16(sum_{z<8} part[z][i]), float4-vectorized.
// ---------------------------------------------------------------------------
__global__ __launch_bounds__(256)
void wct_reduce8(const float* __restrict__ part, ushortT* __restrict__ Wct_t)
{
    const int i = blockIdx.x * 256 + threadIdx.x;       // 65536 float4-groups
    float4 s = *reinterpret_cast<const float4*>(part + (size_t)i * 4);
    #pragma unroll
    for (int z = 1; z < 8; ++z) {
        float4 v = *reinterpret_cast<const float4*>(part + (size_t)z * 262144 + (size_t)i * 4);
        s.x += v.x; s.y += v.y; s.z += v.z; s.w += v.w;
    }
    short4v ov = { (short)f2bf(s.x), (short)f2bf(s.y),
                   (short)f2bf(s.z), (short)f2bf(s.w) };
    *reinterpret_cast<short4v*>(Wct_t + (size_t)i * 4) = ov;
}

// ---------------------------------------------------------------------------
// 3) conv_direct v3: fmap2[gp][o] = sum_c fmap[b(gp)][c][p(gp)] * Wct_t[o][c]
//    BOTH tiles DMA-staged in LDS (R18 lesson: VGPR prefetch gets serialized;
//    only global_load_lds survives regalloc). v3 vs R17-v1: wave w owns gp
//    rows w*16..+15 and ALL 128 o (was: all waves read identical A frags) ->
//    A-side scalar ds_read/cvt traffic drops 4x; W b128 reads (cheap,
//    conflict-free gemm-v4 layout) absorb the o-sweep. 16 MFMA/wave/step.
// ---------------------------------------------------------------------------
__global__ __launch_bounds__(256, 2)
void conv_direct(const float* __restrict__ fmap, const ushortT* __restrict__ Wct_t,
                 ushortT* __restrict__ fmap2)
{
    __shared__ float   Pf[2][64 * 64];      // 16KB x2: [c][16 slots x 4 f32]
    __shared__ ushortT Wb[2][128 * 64];     // 16KB x2: [o][8 chunks] XOR rows
    const int tid  = threadIdx.x;
    const int wid  = tid >> 6;
    const int lane = tid & 63;
    const int fr   = lane & 15;
    const int kq   = lane >> 4;

    // 784 blocks = 392 gp-tiles x 2 o-halves; pairs adjacent on one XCD.
    const int i   = blockIdx.x;
    const int w   = (i & 7) * 98 + (i >> 3);
    const int gp0 = (w >> 1) * 64;
    const int o0  = (w & 1) * 128;

    // hoisted k0-invariant staging sources
    const float* psrc[4];
    const ushortT* wsrc[4];
    #pragma unroll
    for (int q = 0; q < 4; ++q) {
        int id = q * 256 + tid;
        int c  = id >> 4;                       // 0..63
        int js = id & 15;                       // slot
        int x  = (c + 4 * (c >> 3)) & 15;
        int j  = js ^ x;                        // granule within tile
        int gg = (gp0 >> 2) + j;                // global granule
        int bb = gg / 49;
        int p4g = gg - bb * 49;
        psrc[q] = fmap + ((size_t)bb * 1024 + c) * 196 + p4g * 4;
        int row = id >> 3;                      // 0..127 (o)
        int kcs = (id & 7) ^ (row & 7);
        wsrc[q] = Wct_t + (size_t)(o0 + row) * 1024 + kcs * 8;
    }

    auto stage = [&](int k0, int buf) {
        #pragma unroll
        for (int q = 0; q < 4; ++q) {
            int id = q * 256 + tid;
            gload_lds16(psrc[q] + (size_t)k0 * 196, (char*)&Pf[buf][0] + id * 16);
            gload_lds16(wsrc[q] + k0,               (char*)&Wb[buf][0] + id * 16);
        }
    };

    const int rx = fr & 7;
    auto wread = [&](const ushortT* WB, int n, int ks) -> bf16x8 {
        int wo = n * 16 + fr;                   // 0..127 (all o this wave)
        int c4 = ((ks << 2) + kq) ^ rx;         // wo&7 == fr&7 == rx
        return *reinterpret_cast<const bf16x8*>(&WB[(wo << 6) + (c4 << 3)]);
    };
    const int p4b = fr >> 2, pr = fr & 3;
    auto aread = [&](const float* PB, int m, int ks) -> bf16x8 {
        const int p4 = m * 4 + p4b;
        bf16x8 a;
        #pragma unroll
        for (int i2 = 0; i2 < 8; ++i2) {
            int x = (i2 + 12 * kq) & 15;        // == (c+4*(c>>3))&15 for this c
            int c = ks * 32 + kq * 8 + i2;
            a[i2] = (__bf16)PB[(c << 6) + ((p4 ^ x) << 2) + pr];
        }
        return a;
    };

    f32x4 acc[8];
    #pragma unroll
    for (int n = 0; n < 8; ++n) acc[n] = (f32x4){0,0,0,0};

    auto domfma = [&](const float* PB, const ushortT* WB) {
        bf16x8 a0 = aread(PB, wid, 0);
        bf16x8 a1 = aread(PB, wid, 1);
        #pragma unroll
        for (int n = 0; n < 8; ++n) {
            acc[n] = __builtin_amdgcn_mfma_f32_16x16x32_bf16(a0, wread(WB, n, 0), acc[n], 0, 0, 0);
            acc[n] = __builtin_amdgcn_mfma_f32_16x16x32_bf16(a1, wread(WB, n, 1), acc[n], 0, 0, 0);
        }
    };

    stage(0, 0);
    __syncthreads();

    #pragma unroll 1
    for (int t = 0; t < 16; ++t) {
        const int cur = t & 1, nxt = cur ^ 1;
        if (t < 15) stage((t + 1) * 64, nxt);
        domfma(Pf[cur], Wb[cur]);
        __syncthreads();
    }

    // D: col=fr (o within n-tile), row=kq*4+jj (gp within wave's 16)  [m89/m91]
    const int gp = gp0 + wid * 16 + kq * 4;
    #pragma unroll
    for (int n = 0; n < 8; ++n) {
        const int o = o0 + n * 16 + fr;
        #pragma unroll
        for (int jj = 0; jj < 4; ++jj)
            fmap2[(size_t)(gp + jj) * 256 + o] = f2bf(acc[n][jj]);
    }
}

// ---------------------------------------------------------------------------
// 4) roi_lite: fmap2 bf16 [25088][256] -> pooled [4096][9*256] bf16
// ---------------------------------------------------------------------------
__global__ __launch_bounds__(256)
void roi_lite(const ushortT* __restrict__ fmap2, const float* __restrict__ boxes,
              ushortT* __restrict__ pooled)
{
    __shared__ ushortT tile[196][72];
    const int b   = blockIdx.x >> 2;
    const int o0  = (blockIdx.x & 3) << 6;
    const int tid = threadIdx.x;

    const ushortT* src = fmap2 + (size_t)b * 196 * 256 + o0;
    #pragma unroll
    for (int i = 0; i < 7; ++i) {
        int chunk = tid + (i << 8);
        if (chunk < 1568) {
            int p  = chunk >> 3;
            int c8 = (chunk & 7) << 3;
            short8 v = *reinterpret_cast<const short8*>(src + (size_t)p * 256 + c8);
            *reinterpret_cast<short8*>(&tile[p][c8]) = v;
        }
    }
    __syncthreads();

    const int box = tid >> 3;
    const int ch8 = (tid & 7) << 3;
    const int k   = (b << 5) + box;
    const float* bx = boxes + (size_t)k * 4;
    float x1 = fminf(fmaxf(bx[0], 0.f), 14.f);
    float y1 = fminf(fmaxf(bx[1], 0.f), 14.f);
    float x2 = fminf(fmaxf(bx[2], 0.f), 14.f);
    float y2 = fminf(fmaxf(bx[3], 0.f), 14.f);
    float bw = fmaxf(x2 - x1, 1.f) * (1.0f / 3.0f);
    float bh = fmaxf(y2 - y1, 1.f) * (1.0f / 3.0f);

    int   ylo[6], xlo[6];
    float wylo[6], wyhi[6], wxlo[6], wxhi[6];
    #pragma unroll
    for (int i = 0; i < 6; ++i) {
        float off = (i & 1) ? 0.75f : 0.25f;
        float pf  = (float)(i >> 1);
        float yc = y1 + (pf + off) * bh;
        bool  vy = (yc > -1.0f) && (yc < 14.f);
        float cy = fminf(fmaxf(yc, 0.f), 13.f);
        int   lo = (int)floorf(cy); if (lo > 12) lo = 12;
        float fy = cy - (float)lo;
        ylo[i]  = lo;
        wylo[i] = vy ? 1.f - fy : 0.f;
        wyhi[i] = vy ? fy       : 0.f;
        float xc = x1 + (pf + off) * bw;
        bool  vx = (xc > -1.0f) && (xc < 14.f);
        float cx = fminf(fmaxf(xc, 0.f), 13.f);
        int   lx = (int)floorf(cx); if (lx > 12) lx = 12;
        float fx = cx - (float)lx;
        xlo[i]  = lx;
        wxlo[i] = vx ? 1.f - fx : 0.f;
        wxhi[i] = vx ? fx       : 0.f;
    }

    float acc[3][3][8] = {};
    #pragma unroll
    for (int i = 0; i < 6; ++i) {
        #pragma unroll
        for (int j = 0; j < 6; ++j) {
            const int plo = ylo[i] * 14 + xlo[j];
            const float w00 = wylo[i] * wxlo[j];
            const float w01 = wylo[i] * wxhi[j];
            const float w10 = wyhi[i] * wxlo[j];
            const float w11 = wyhi[i] * wxhi[j];
            short8 v00 = *reinterpret_cast<const short8*>(&tile[plo][ch8]);
            short8 v01 = *reinterpret_cast<const short8*>(&tile[plo + 1][ch8]);
            short8 v10 = *reinterpret_cast<const short8*>(&tile[plo + 14][ch8]);
            short8 v11 = *reinterpret_cast<const short8*>(&tile[plo + 15][ch8]);
            #pragma unroll
            for (int c = 0; c < 8; ++c) {
                float a = acc[i >> 1][j >> 1][c];
                a = fmaf(bf2f((ushortT)v00[c]), w00, a);
                a = fmaf(bf2f((ushortT)v01[c]), w01, a);
                a = fmaf(bf2f((ushortT)v10[c]), w10, a);
                a = fmaf(bf2f((ushortT)v11[c]), w11, a);
                acc[i >> 1][j >> 1][c] = a;
            }
        }
    }

    ushortT* outp = pooled + (size_t)k * 2304 + o0 + ch8;
    #pragma unroll
    for (int p = 0; p < 3; ++p) {
        #pragma unroll
        for (int q = 0; q < 3; ++q) {
            short8 ov;
            #pragma unroll
            for (int c = 0; c < 8; ++c) ov[c] = (short)f2bf(acc[p][q][c] * 0.25f);
            *reinterpret_cast<short8*>(outp + (size_t)(p * 3 + q) * 256) = ov;
        }
    }
}

// ---------------------------------------------------------------------------
// 5) gemm_mfma v4 (fc1): C[M][N] = A[M][K]*Bt[N][K]^T, tile 128x64, swizzled.
// ---------------------------------------------------------------------------
template<int RELU, int BIAS>
__global__ __launch_bounds__(256, 2)
void gemm_mfma(const ushortT* __restrict__ A, const ushortT* __restrict__ Bt,
               ushortT* __restrict__ C, const float* __restrict__ bias,
               int M, int N, int K)
{
    __shared__ ushortT As[2][128 * 64];    // 16KB x2
    const int tid  = threadIdx.x;
    const int wid  = tid >> 6;
    const int lane = tid & 63;
    const int ncolb = N >> 6;
    const int nblk  = (M >> 7) * ncolb;
    const int cpx   = nblk >> 3;
    const int i     = blockIdx.x;
    const int w     = (i & 7) * cpx + (i >> 3);
    const size_t row0 = (size_t)(w / ncolb) * 128;
    const size_t col0 = (size_t)(w % ncolb) * 64;

    const ushortT* agbase = A + row0 * K;
    auto stage = [&](int k0, int buf) {
        #pragma unroll
        for (int q = 0; q < 4; ++q) {
            int id  = q * 256 + tid;
            int row = id >> 3;
            int kcs = (id & 7) ^ (row & 7);
            gload_lds16(agbase + (size_t)row * K + k0 + kcs * 8,
                        As[buf] + id * 8);
        }
    };

    const int fr = lane & 15;
    const int kq = lane >> 4;
    const int rx = fr & 7;
    auto lda = [&](const ushortT* Ab, int m, int s) -> bf16x8 {
        const int r = m * 16 + fr;
        const int c = (s << 2) + kq;
        return *reinterpret_cast<const bf16x8*>(&Ab[(r << 6) + ((c ^ rx) << 3)]);
    };

    const ushortT* bbase = Bt + (col0 + wid * 16 + fr) * (size_t)K + kq * 8;
    auto loadB2 = [&](int k0, bf16x8& r0, bf16x8& r1) {
        r0 = *reinterpret_cast<const bf16x8*>(bbase + k0);
        r1 = *reinterpret_cast<const bf16x8*>(bbase + k0 + 32);
    };

    f32x4 acc[8];
    #pragma unroll
    for (int m = 0; m < 8; ++m) acc[m] = (f32x4){0,0,0,0};

    auto domfma = [&](const ushortT* Ab, bf16x8 b0, bf16x8 b1) {
        #pragma unroll
        for (int m = 0; m < 8; ++m) {
            acc[m] = __builtin_amdgcn_mfma_f32_16x16x32_bf16(lda(Ab, m, 0), b0, acc[m], 0, 0, 0);
            acc[m] = __builtin_amdgcn_mfma_f32_16x16x32_bf16(lda(Ab, m, 1), b1, acc[m], 0, 0, 0);
        }
    };

    const int nsteps = K >> 6;
    bf16x8 bA0, bA1, bB0, bB1;
    stage(0, 0);
    loadB2(0, bA0, bA1);
    __syncthreads();

    #pragma unroll 1
    for (int s = 0; s < (nsteps >> 1); ++s) {
        const int t = 2 * s;
        if (t + 1 < nsteps) { stage((t + 1) * 64, 1); loadB2((t + 1) * 64, bB0, bB1); }
        domfma(As[0], bA0, bA1);
        __syncthreads();
        if (t + 2 < nsteps) { stage((t + 2) * 64, 0); loadB2((t + 2) * 64, bA0, bA1); }
        domfma(As[1], bB0, bB1);
        __syncthreads();
    }

    const int orow = kq * 4;
    const size_t col = col0 + wid * 16 + fr;
    float bv = 0.f;
    if (BIAS) bv = bias[col];
    #pragma unroll
    for (int m = 0; m < 8; ++m) {
        const size_t rbase = row0 + m * 16 + orow;
        #pragma unroll
        for (int j = 0; j < 4; ++j) {
            float v = acc[m][j] + bv;
            if (RELU) v = fmaxf(v, 0.f);
            C[(rbase + j) * N + col] = f2bf(v);
        }
    }
}

// ---------------------------------------------------------------------------
// 6) fc2: out[4096][27] f32 = h[4096][1024] @ w[1024][27] + b
// ---------------------------------------------------------------------------
__global__ __launch_bounds__(256)
void fc2_kernel(const ushortT* __restrict__ h, const float* __restrict__ w,
                const float* __restrict__ bias, float* __restrict__ out)
{
    __shared__ float   Wsm[128][32];
    __shared__ ushortT Hs[16][136];
    const int tid  = threadIdx.x;
    const int row0 = blockIdx.x * 16;
    const int r    = tid >> 4;
    const int jg   = tid & 15;
    float accx = 0.f, accy = 0.f;

    const int kk2  = tid >> 1;
    const int half = tid & 1;

    for (int k0 = 0; k0 < 1024; k0 += 128) {
        if (half == 0) {
            #pragma unroll
            for (int j = 0; j < 14; ++j)
                Wsm[kk2][j] = w[(size_t)(k0 + kk2) * 27 + j];
        } else {
            #pragma unroll
            for (int j = 14; j < 27; ++j)
                Wsm[kk2][j] = w[(size_t)(k0 + kk2) * 27 + j];
            #pragma unroll
            for (int j = 27; j < 32; ++j) Wsm[kk2][j] = 0.f;
        }
        {
            int hr = tid >> 4, hc = tid & 15;
            short8 v = *reinterpret_cast<const short8*>(
                h + (size_t)(row0 + hr) * 1024 + k0 + hc * 8);
            *reinterpret_cast<short8*>(&Hs[hr][hc * 8]) = v;
        }
        __syncthreads();
        #pragma unroll 8
        for (int kk = 0; kk < 128; ++kk) {
            float  hv = bf2f(Hs[r][kk]);
            float2 wv = *reinterpret_cast<const float2*>(&Wsm[kk][jg * 2]);
            accx = fmaf(hv, wv.x, accx);
            accy = fmaf(hv, wv.y, accy);
        }
        __syncthreads();
    }
    const int j0 = jg * 2;
    float* op = out + (size_t)(row0 + r) * 27;
    if (j0 < 27)     op[j0]     = accx + bias[j0];
    if (j0 + 1 < 27) op[j0 + 1] = accy + bias[j0 + 1];
}

// ---------------------------------------------------------------------------
extern "C" void kernel_launch(void* const* d_in, const int* in_sizes, int n_in,
                              void* d_out, int out_size, void* d_ws, size_t ws_size,
                              hipStream_t stream)
{
    (void)in_sizes; (void)n_in; (void)out_size; (void)ws_size;
    const float* fmap  = (const float*)d_in[0];
    const float* boxes = (const float*)d_in[1];
    const float* w_c1  = (const float*)d_in[2];
    const float* w_c2  = (const float*)d_in[3];
    const float* w_fc1 = (const float*)d_in[4];
    const float* b_fc1 = (const float*)d_in[5];
    const float* w_fc2 = (const float*)d_in[6];
    const float* b_fc2 = (const float*)d_in[7];
    float* out = (float*)d_out;

    char* ws = (char*)d_ws;
    size_t off = 0;
    ushortT* fmap2  = (ushortT*)(ws + off); off += (size_t)25088 * 256 * 2;   // 12,845,056
    ushortT* pooled = (ushortT*)(ws + off); off += (size_t)4096 * 2304 * 2;   // 18,874,368
    ushortT* hbuf   = (ushortT*)(ws + off); off += (size_t)4096 * 1024 * 2;   //  8,388,608
    ushortT* Wct_t  = (ushortT*)(ws + off); off += (size_t)256 * 1024 * 2;    //    524,288
    ushortT* wp_t   = (ushortT*)(ws + off); off += (size_t)1024 * 2304 * 2;   //  4,718,592
    float*   wpart  = (float*)(ws + off);   off += (size_t)8 * 262144 * 4;    //  8,388,608

    hipLaunchKernelGGL(prep_fused,  dim3(1088), dim3(256), 0, stream,
                       w_c1, w_c2, w_fc1, wpart, wp_t);
    hipLaunchKernelGGL(wct_reduce8, dim3(256),  dim3(256), 0, stream, wpart, Wct_t);

    // conv (transpose fused): fmap2[25088 x 256] from fmap f32 directly
    hipLaunchKernelGGL(conv_direct, dim3(784),  dim3(256), 0, stream,
                       fmap, Wct_t, fmap2);
    hipLaunchKernelGGL(roi_lite,    dim3(512),  dim3(256), 0, stream, fmap2, boxes, pooled);
    // fc1: hbuf[4096 x 1024] = pooled[4096 x 2304] * wp_t[1024 x 2304]^T (+bias, relu)
    hipLaunchKernelGGL((gemm_mfma<1,1>), dim3(512), dim3(256), 0, stream,
                       pooled, wp_t, hbuf, b_fc1, 4096, 1024, 2304);
    hipLaunchKernelGGL(fc2_kernel,  dim3(256),  dim3(256), 0, stream,
                       hbuf, w_fc2, b_fc2, out);
}

// Round 20
// 130.305 us; speedup vs baseline: 1.2950x; 1.0184x over previous
//
#include <hip/hip_runtime.h>

typedef unsigned short ushortT;
typedef __attribute__((ext_vector_type(8))) short short8;
typedef __attribute__((ext_vector_type(4))) short short4v;
typedef __attribute__((ext_vector_type(8))) __bf16 bf16x8;
typedef __attribute__((ext_vector_type(4))) float f32x4;

__device__ __forceinline__ float bf2f(ushortT u) {
    unsigned int x = ((unsigned int)u) << 16;
    return __builtin_bit_cast(float, x);
}
__device__ __forceinline__ ushortT f2bf(float f) {
    unsigned int x = __builtin_bit_cast(unsigned int, f);
    unsigned int r = (x + 0x7FFFu + ((x >> 16) & 1u)) >> 16;
    return (ushortT)r;
}

__device__ __forceinline__ void gload_lds16(const void* g, void* l) {
    __builtin_amdgcn_global_load_lds(
        (const __attribute__((address_space(1))) void*)g,
        (__attribute__((address_space(3))) void*)l, 16, 0, 0);
}

// ---------------------------------------------------------------------------
// 1) prep_fused: [0,512) wct_part split-K x8; [512,1088) permute_fc1.
// ---------------------------------------------------------------------------
__global__ __launch_bounds__(256)
void prep_fused(const float* __restrict__ w_c1, const float* __restrict__ w_c2,
                const float* __restrict__ w_fc1,
                float* __restrict__ wpart, ushortT* __restrict__ wpt)
{
    __shared__ __align__(16) char smem[33280];
    const int blk = blockIdx.x;
    const int tid = threadIdx.x;

    if (blk < 512) {
        auto w2s = reinterpret_cast<float(*)[65]>(smem);           // [64][65]
        auto w1s = reinterpret_cast<float(*)[65]>(smem + 16640);   // [64][65]
        const int idx = blk;
        const int o0 = (idx & 3) * 64;
        const int c0 = ((idx >> 2) & 15) * 64;
        const int z  = idx >> 6;             // 0..7
        const int m0 = z * 64;
        const int ty = tid >> 4, tx = tid & 15;
        float acc[4][4] = {};
        #pragma unroll
        for (int c4 = 0; c4 < 4; ++c4) {
            int id2 = c4 * 256 + tid;
            int row = id2 >> 4, f4 = id2 & 15;
            float4 v = *reinterpret_cast<const float4*>(
                w_c2 + (size_t)(o0 + row) * 512 + m0 + f4 * 4);
            w2s[row][f4*4+0] = v.x; w2s[row][f4*4+1] = v.y;
            w2s[row][f4*4+2] = v.z; w2s[row][f4*4+3] = v.w;
            float4 u = *reinterpret_cast<const float4*>(
                w_c1 + (size_t)(m0 + row) * 1024 + c0 + f4 * 4);
            w1s[row][f4*4+0] = u.x; w1s[row][f4*4+1] = u.y;
            w1s[row][f4*4+2] = u.z; w1s[row][f4*4+3] = u.w;
        }
        __syncthreads();
        for (int m = 0; m < 64; ++m) {
            float a[4], b[4];
            #pragma unroll
            for (int i = 0; i < 4; ++i) a[i] = w2s[ty*4+i][m];
            #pragma unroll
            for (int j = 0; j < 4; ++j) b[j] = w1s[m][tx*4+j];
            #pragma unroll
            for (int i = 0; i < 4; ++i)
                #pragma unroll
                for (int j = 0; j < 4; ++j) acc[i][j] = fmaf(a[i], b[j], acc[i][j]);
        }
        float* dst = wpart + (size_t)z * 262144;
        #pragma unroll
        for (int i = 0; i < 4; ++i) {
            float4 ov = { acc[i][0], acc[i][1], acc[i][2], acc[i][3] };
            *reinterpret_cast<float4*>(dst + (size_t)(o0 + ty*4 + i) * 1024 + c0 + tx*4) = ov;
        }
    } else {
        auto tile = reinterpret_cast<float(*)[65]>(smem);          // [64][65]
        const int idx = blk - 512;                                  // 0..575
        const int cib = idx % 36;
        const int ci0 = cib * 64;
        const int j0  = (idx / 36) * 64;
        const int hw  = ci0 >> 8;
        const int o0  = ci0 & 255;
        #pragma unroll
        for (int c4 = 0; c4 < 4; ++c4) {
            int id2 = c4 * 256 + tid;
            int row = id2 >> 4;
            int f4  = id2 & 15;
            float4 v = *reinterpret_cast<const float4*>(
                w_fc1 + (size_t)((o0 + row) * 9 + hw) * 1024 + j0 + f4 * 4);
            tile[row][f4*4+0] = v.x; tile[row][f4*4+1] = v.y;
            tile[row][f4*4+2] = v.z; tile[row][f4*4+3] = v.w;
        }
        __syncthreads();
        #pragma unroll
        for (int c4 = 0; c4 < 4; ++c4) {
            int id2 = c4 * 256 + tid;
            int j   = id2 >> 4;
            int og  = id2 & 15;
            short4v ov;
            #pragma unroll
            for (int i = 0; i < 4; ++i) ov[i] = (short)f2bf(tile[og*4+i][j]);
            *reinterpret_cast<short4v*>(wpt + (size_t)(j0 + j) * 2304 + ci0 + og*4) = ov;
        }
    }
}

// ---------------------------------------------------------------------------
// 2) wct_reduce8: Wct_t[i] = bf16(sum_{z<8} part[z][i]), float4-vectorized.
// ---------------------------------------------------------------------------
__global__ __launch_bounds__(256)
void wct_reduce8(const float* __restrict__ part, ushortT* __restrict__ Wct_t)
{
    const int i = blockIdx.x * 256 + threadIdx.x;       // 65536 float4-groups
    float4 s = *reinterpret_cast<const float4*>(part + (size_t)i * 4);
    #pragma unroll
    for (int z = 1; z < 8; ++z) {
        float4 v = *reinterpret_cast<const float4*>(part + (size_t)z * 262144 + (size_t)i * 4);
        s.x += v.x; s.y += v.y; s.z += v.z; s.w += v.w;
    }
    short4v ov = { (short)f2bf(s.x), (short)f2bf(s.y),
                   (short)f2bf(s.z), (short)f2bf(s.w) };
    *reinterpret_cast<short4v*>(Wct_t + (size_t)i * 4) = ov;
}

// ---------------------------------------------------------------------------
// 3) conv_direct v4: fmap2[gp][o] = sum_c fmap[b(gp)][c][p(gp)] * Wct_t[o][c]
//    Occupancy experiment: BK=32, LDS 32KB total -> ~5 blocks/CU (20 waves)
//    vs v3's 2 (16% occ). Both tiles DMA-staged (R18 lesson: VGPR prefetch
//    gets re-serialized; only global_load_lds survives regalloc).
//    P slot XOR x(c)=(c+4(c>>3))&15 (R17-verified, conflict-free);
//    W rows 64B, read chunk' = kq^(wo&3) -> uniform 8 lanes/bank-quad.
// ---------------------------------------------------------------------------
__global__ __launch_bounds__(256, 4)
void conv_direct(const float* __restrict__ fmap, const ushortT* __restrict__ Wct_t,
                 ushortT* __restrict__ fmap2)
{
    __shared__ float   Pf[2][32 * 64];      // 8KB x2: [c][16 slots x 4 f32]
    __shared__ ushortT Wb[2][128 * 32];     // 8KB x2: [o][4 chunks] XOR rows
    const int tid  = threadIdx.x;
    const int wid  = tid >> 6;
    const int lane = tid & 63;
    const int fr   = lane & 15;
    const int kq   = lane >> 4;

    // 784 blocks = 392 gp-tiles x 2 o-halves; pairs adjacent on one XCD.
    const int i   = blockIdx.x;
    const int w   = (i & 7) * 98 + (i >> 3);
    const int gp0 = (w >> 1) * 64;
    const int o0  = (w & 1) * 128;

    // hoisted k0-invariant staging sources (both with source-side involutions)
    const float* psrc[2];
    const ushortT* wsrc[2];
    #pragma unroll
    for (int q = 0; q < 2; ++q) {
        int id = q * 256 + tid;                 // 0..511
        int c  = id >> 4;                       // 0..31
        int js = id & 15;                       // slot
        int x  = (c + 4 * (c >> 3)) & 15;
        int j  = js ^ x;                        // granule within tile
        int gg = (gp0 >> 2) + j;                // global granule
        int bb = gg / 49;
        int p4g = gg - bb * 49;
        psrc[q] = fmap + ((size_t)bb * 1024 + c) * 196 + p4g * 4;
        int row = id >> 2;                      // 0..127 (o)
        int kc  = id & 3;
        int kcs = kc ^ (row & 3);
        wsrc[q] = Wct_t + (size_t)(o0 + row) * 1024 + kcs * 8;
    }

    auto stage = [&](int k0, int buf) {
        #pragma unroll
        for (int q = 0; q < 2; ++q) {
            int id = q * 256 + tid;
            gload_lds16(psrc[q] + (size_t)k0 * 196, (char*)&Pf[buf][0] + id * 16);
            gload_lds16(wsrc[q] + k0,               (char*)&Wb[buf][0] + id * 16);
        }
    };

    auto wread = [&](const ushortT* WB, int n) -> bf16x8 {
        int wo = n * 16 + fr;                   // 0..127 (all o this wave)
        int cq = kq ^ (fr & 3);                 // wo&3 == fr&3
        return *reinterpret_cast<const bf16x8*>(&WB[(wo << 5) + (cq << 3)]);
    };
    const int p4b = fr >> 2, pr = fr & 3;
    auto aread = [&](const float* PB) -> bf16x8 {
        const int p4 = wid * 4 + p4b;
        bf16x8 a;
        #pragma unroll
        for (int i2 = 0; i2 < 8; ++i2) {
            int x = (i2 + 12 * kq) & 15;        // == (c+4*(c>>3))&15, c=kq*8+i2
            int c = kq * 8 + i2;
            a[i2] = (__bf16)PB[(c << 6) + ((p4 ^ x) << 2) + pr];
        }
        return a;
    };

    f32x4 acc[8];
    #pragma unroll
    for (int n = 0; n < 8; ++n) acc[n] = (f32x4){0,0,0,0};

    stage(0, 0);
    __syncthreads();

    #pragma unroll 1
    for (int t = 0; t < 32; ++t) {
        const int cur = t & 1, nxt = cur ^ 1;
        if (t < 31) stage((t + 1) * 32, nxt);
        bf16x8 a = aread(Pf[cur]);
        #pragma unroll
        for (int n = 0; n < 8; ++n)
            acc[n] = __builtin_amdgcn_mfma_f32_16x16x32_bf16(a, wread(Wb[cur], n), acc[n], 0, 0, 0);
        __syncthreads();
    }

    // D: col=fr (o within n-tile), row=kq*4+jj (gp within wave's 16)  [m89/m91]
    const int gp = gp0 + wid * 16 + kq * 4;
    #pragma unroll
    for (int n = 0; n < 8; ++n) {
        const int o = o0 + n * 16 + fr;
        #pragma unroll
        for (int jj = 0; jj < 4; ++jj)
            fmap2[(size_t)(gp + jj) * 256 + o] = f2bf(acc[n][jj]);
    }
}

// ---------------------------------------------------------------------------
// 4) roi_lite: fmap2 bf16 [25088][256] -> pooled [4096][9*256] bf16
// ---------------------------------------------------------------------------
__global__ __launch_bounds__(256)
void roi_lite(const ushortT* __restrict__ fmap2, const float* __restrict__ boxes,
              ushortT* __restrict__ pooled)
{
    __shared__ ushortT tile[196][72];
    const int b   = blockIdx.x >> 2;
    const int o0  = (blockIdx.x & 3) << 6;
    const int tid = threadIdx.x;

    const ushortT* src = fmap2 + (size_t)b * 196 * 256 + o0;
    #pragma unroll
    for (int i = 0; i < 7; ++i) {
        int chunk = tid + (i << 8);
        if (chunk < 1568) {
            int p  = chunk >> 3;
            int c8 = (chunk & 7) << 3;
            short8 v = *reinterpret_cast<const short8*>(src + (size_t)p * 256 + c8);
            *reinterpret_cast<short8*>(&tile[p][c8]) = v;
        }
    }
    __syncthreads();

    const int box = tid >> 3;
    const int ch8 = (tid & 7) << 3;
    const int k   = (b << 5) + box;
    const float* bx = boxes + (size_t)k * 4;
    float x1 = fminf(fmaxf(bx[0], 0.f), 14.f);
    float y1 = fminf(fmaxf(bx[1], 0.f), 14.f);
    float x2 = fminf(fmaxf(bx[2], 0.f), 14.f);
    float y2 = fminf(fmaxf(bx[3], 0.f), 14.f);
    float bw = fmaxf(x2 - x1, 1.f) * (1.0f / 3.0f);
    float bh = fmaxf(y2 - y1, 1.f) * (1.0f / 3.0f);

    int   ylo[6], xlo[6];
    float wylo[6], wyhi[6], wxlo[6], wxhi[6];
    #pragma unroll
    for (int i = 0; i < 6; ++i) {
        float off = (i & 1) ? 0.75f : 0.25f;
        float pf  = (float)(i >> 1);
        float yc = y1 + (pf + off) * bh;
        bool  vy = (yc > -1.0f) && (yc < 14.f);
        float cy = fminf(fmaxf(yc, 0.f), 13.f);
        int   lo = (int)floorf(cy); if (lo > 12) lo = 12;
        float fy = cy - (float)lo;
        ylo[i]  = lo;
        wylo[i] = vy ? 1.f - fy : 0.f;
        wyhi[i] = vy ? fy       : 0.f;
        float xc = x1 + (pf + off) * bw;
        bool  vx = (xc > -1.0f) && (xc < 14.f);
        float cx = fminf(fmaxf(xc, 0.f), 13.f);
        int   lx = (int)floorf(cx); if (lx > 12) lx = 12;
        float fx = cx - (float)lx;
        xlo[i]  = lx;
        wxlo[i] = vx ? 1.f - fx : 0.f;
        wxhi[i] = vx ? fx       : 0.f;
    }

    float acc[3][3][8] = {};
    #pragma unroll
    for (int i = 0; i < 6; ++i) {
        #pragma unroll
        for (int j = 0; j < 6; ++j) {
            const int plo = ylo[i] * 14 + xlo[j];
            const float w00 = wylo[i] * wxlo[j];
            const float w01 = wylo[i] * wxhi[j];
            const float w10 = wyhi[i] * wxlo[j];
            const float w11 = wyhi[i] * wxhi[j];
            short8 v00 = *reinterpret_cast<const short8*>(&tile[plo][ch8]);
            short8 v01 = *reinterpret_cast<const short8*>(&tile[plo + 1][ch8]);
            short8 v10 = *reinterpret_cast<const short8*>(&tile[plo + 14][ch8]);
            short8 v11 = *reinterpret_cast<const short8*>(&tile[plo + 15][ch8]);
            #pragma unroll
            for (int c = 0; c < 8; ++c) {
                float a = acc[i >> 1][j >> 1][c];
                a = fmaf(bf2f((ushortT)v00[c]), w00, a);
                a = fmaf(bf2f((ushortT)v01[c]), w01, a);
                a = fmaf(bf2f((ushortT)v10[c]), w10, a);
                a = fmaf(bf2f((ushortT)v11[c]), w11, a);
                acc[i >> 1][j >> 1][c] = a;
            }
        }
    }

    ushortT* outp = pooled + (size_t)k * 2304 + o0 + ch8;
    #pragma unroll
    for (int p = 0; p < 3; ++p) {
        #pragma unroll
        for (int q = 0; q < 3; ++q) {
            short8 ov;
            #pragma unroll
            for (int c = 0; c < 8; ++c) ov[c] = (short)f2bf(acc[p][q][c] * 0.25f);
            *reinterpret_cast<short8*>(outp + (size_t)(p * 3 + q) * 256) = ov;
        }
    }
}

// ---------------------------------------------------------------------------
// 5) gemm_mfma v4 (fc1): C[M][N] = A[M][K]*Bt[N][K]^T, tile 128x64, swizzled.
// ---------------------------------------------------------------------------
template<int RELU, int BIAS>
__global__ __launch_bounds__(256, 2)
void gemm_mfma(const ushortT* __restrict__ A, const ushortT* __restrict__ Bt,
               ushortT* __restrict__ C, const float* __restrict__ bias,
               int M, int N, int K)
{
    __shared__ ushortT As[2][128 * 64];    // 16KB x2
    const int tid  = threadIdx.x;
    const int wid  = tid >> 6;
    const int lane = tid & 63;
    const int ncolb = N >> 6;
    const int nblk  = (M >> 7) * ncolb;
    const int cpx   = nblk >> 3;
    const int i     = blockIdx.x;
    const int w     = (i & 7) * cpx + (i >> 3);
    const size_t row0 = (size_t)(w / ncolb) * 128;
    const size_t col0 = (size_t)(w % ncolb) * 64;

    const ushortT* agbase = A + row0 * K;
    auto stage = [&](int k0, int buf) {
        #pragma unroll
        for (int q = 0; q < 4; ++q) {
            int id  = q * 256 + tid;
            int row = id >> 3;
            int kcs = (id & 7) ^ (row & 7);
            gload_lds16(agbase + (size_t)row * K + k0 + kcs * 8,
                        As[buf] + id * 8);
        }
    };

    const int fr = lane & 15;
    const int kq = lane >> 4;
    const int rx = fr & 7;
    auto lda = [&](const ushortT* Ab, int m, int s) -> bf16x8 {
        const int r = m * 16 + fr;
        const int c = (s << 2) + kq;
        return *reinterpret_cast<const bf16x8*>(&Ab[(r << 6) + ((c ^ rx) << 3)]);
    };

    const ushortT* bbase = Bt + (col0 + wid * 16 + fr) * (size_t)K + kq * 8;
    auto loadB2 = [&](int k0, bf16x8& r0, bf16x8& r1) {
        r0 = *reinterpret_cast<const bf16x8*>(bbase + k0);
        r1 = *reinterpret_cast<const bf16x8*>(bbase + k0 + 32);
    };

    f32x4 acc[8];
    #pragma unroll
    for (int m = 0; m < 8; ++m) acc[m] = (f32x4){0,0,0,0};

    auto domfma = [&](const ushortT* Ab, bf16x8 b0, bf16x8 b1) {
        #pragma unroll
        for (int m = 0; m < 8; ++m) {
            acc[m] = __builtin_amdgcn_mfma_f32_16x16x32_bf16(lda(Ab, m, 0), b0, acc[m], 0, 0, 0);
            acc[m] = __builtin_amdgcn_mfma_f32_16x16x32_bf16(lda(Ab, m, 1), b1, acc[m], 0, 0, 0);
        }
    };

    const int nsteps = K >> 6;
    bf16x8 bA0, bA1, bB0, bB1;
    stage(0, 0);
    loadB2(0, bA0, bA1);
    __syncthreads();

    #pragma unroll 1
    for (int s = 0; s < (nsteps >> 1); ++s) {
        const int t = 2 * s;
        if (t + 1 < nsteps) { stage((t + 1) * 64, 1); loadB2((t + 1) * 64, bB0, bB1); }
        domfma(As[0], bA0, bA1);
        __syncthreads();
        if (t + 2 < nsteps) { stage((t + 2) * 64, 0); loadB2((t + 2) * 64, bA0, bA1); }
        domfma(As[1], bB0, bB1);
        __syncthreads();
    }

    const int orow = kq * 4;
    const size_t col = col0 + wid * 16 + fr;
    float bv = 0.f;
    if (BIAS) bv = bias[col];
    #pragma unroll
    for (int m = 0; m < 8; ++m) {
        const size_t rbase = row0 + m * 16 + orow;
        #pragma unroll
        for (int j = 0; j < 4; ++j) {
            float v = acc[m][j] + bv;
            if (RELU) v = fmaxf(v, 0.f);
            C[(rbase + j) * N + col] = f2bf(v);
        }
    }
}

// ---------------------------------------------------------------------------
// 6) fc2: out[4096][27] f32 = h[4096][1024] @ w[1024][27] + b
// ---------------------------------------------------------------------------
__global__ __launch_bounds__(256)
void fc2_kernel(const ushortT* __restrict__ h, const float* __restrict__ w,
                const float* __restrict__ bias, float* __restrict__ out)
{
    __shared__ float   Wsm[128][32];
    __shared__ ushortT Hs[16][136];
    const int tid  = threadIdx.x;
    const int row0 = blockIdx.x * 16;
    const int r    = tid >> 4;
    const int jg   = tid & 15;
    float accx = 0.f, accy = 0.f;

    const int kk2  = tid >> 1;
    const int half = tid & 1;

    for (int k0 = 0; k0 < 1024; k0 += 128) {
        if (half == 0) {
            #pragma unroll
            for (int j = 0; j < 14; ++j)
                Wsm[kk2][j] = w[(size_t)(k0 + kk2) * 27 + j];
        } else {
            #pragma unroll
            for (int j = 14; j < 27; ++j)
                Wsm[kk2][j] = w[(size_t)(k0 + kk2) * 27 + j];
            #pragma unroll
            for (int j = 27; j < 32; ++j) Wsm[kk2][j] = 0.f;
        }
        {
            int hr = tid >> 4, hc = tid & 15;
            short8 v = *reinterpret_cast<const short8*>(
                h + (size_t)(row0 + hr) * 1024 + k0 + hc * 8);
            *reinterpret_cast<short8*>(&Hs[hr][hc * 8]) = v;
        }
        __syncthreads();
        #pragma unroll 8
        for (int kk = 0; kk < 128; ++kk) {
            float  hv = bf2f(Hs[r][kk]);
            float2 wv = *reinterpret_cast<const float2*>(&Wsm[kk][jg * 2]);
            accx = fmaf(hv, wv.x, accx);
            accy = fmaf(hv, wv.y, accy);
        }
        __syncthreads();
    }
    const int j0 = jg * 2;
    float* op = out + (size_t)(row0 + r) * 27;
    if (j0 < 27)     op[j0]     = accx + bias[j0];
    if (j0 + 1 < 27) op[j0 + 1] = accy + bias[j0 + 1];
}

// ---------------------------------------------------------------------------
extern "C" void kernel_launch(void* const* d_in, const int* in_sizes, int n_in,
                              void* d_out, int out_size, void* d_ws, size_t ws_size,
                              hipStream_t stream)
{
    (void)in_sizes; (void)n_in; (void)out_size; (void)ws_size;
    const float* fmap  = (const float*)d_in[0];
    const float* boxes = (const float*)d_in[1];
    const float* w_c1  = (const float*)d_in[2];
    const float* w_c2  = (const float*)d_in[3];
    const float* w_fc1 = (const float*)d_in[4];
    const float* b_fc1 = (const float*)d_in[5];
    const float* w_fc2 = (const float*)d_in[6];
    const float* b_fc2 = (const float*)d_in[7];
    float* out = (float*)d_out;

    char* ws = (char*)d_ws;
    size_t off = 0;
    ushortT* fmap2  = (ushortT*)(ws + off); off += (size_t)25088 * 256 * 2;   // 12,845,056
    ushortT* pooled = (ushortT*)(ws + off); off += (size_t)4096 * 2304 * 2;   // 18,874,368
    ushortT* hbuf   = (ushortT*)(ws + off); off += (size_t)4096 * 1024 * 2;   //  8,388,608
    ushortT* Wct_t  = (ushortT*)(ws + off); off += (size_t)256 * 1024 * 2;    //    524,288
    ushortT* wp_t   = (ushortT*)(ws + off); off += (size_t)1024 * 2304 * 2;   //  4,718,592
    float*   wpart  = (float*)(ws + off);   off += (size_t)8 * 262144 * 4;    //  8,388,608

    hipLaunchKernelGGL(prep_fused,  dim3(1088), dim3(256), 0, stream,
                       w_c1, w_c2, w_fc1, wpart, wp_t);
    hipLaunchKernelGGL(wct_reduce8, dim3(256),  dim3(256), 0, stream, wpart, Wct_t);

    // conv (transpose fused): fmap2[25088 x 256] from fmap f32 directly
    hipLaunchKernelGGL(conv_direct, dim3(784),  dim3(256), 0, stream,
                       fmap, Wct_t, fmap2);
    hipLaunchKernelGGL(roi_lite,    dim3(512),  dim3(256), 0, stream, fmap2, boxes, pooled);
    // fc1: hbuf[4096 x 1024] = pooled[4096 x 2304] * wp_t[1024 x 2304]^T (+bias, relu)
    hipLaunchKernelGGL((gemm_mfma<1,1>), dim3(512), dim3(256), 0, stream,
                       pooled, wp_t, hbuf, b_fc1, 4096, 1024, 2304);
    hipLaunchKernelGGL(fc2_kernel,  dim3(256),  dim3(256), 0, stream,
                       hbuf, w_fc2, b_fc2, out);
}